// Round 3
// baseline (908.655 us; speedup 1.0000x reference)
//
#include <hip/hip_runtime.h>
#include <hip/hip_bf16.h>
#include <stdint.h>

typedef unsigned short ushort;
typedef unsigned int uint;

#define N_NODES 100000
#define N_EDGES 1600000
#define KDIM 192      // 3 * 64 concatenated h_j
#define HIDDEN 512
#define NCHUNK 782    // ceil(N/128)
#define SDIM (KDIM*KDIM)

typedef __attribute__((ext_vector_type(8))) short short8;
typedef __attribute__((ext_vector_type(4))) short short4v;
typedef __attribute__((ext_vector_type(4))) float float4v;

__device__ __forceinline__ float bf2f(ushort u){
    uint x = ((uint)u) << 16;
    return __builtin_bit_cast(float, x);
}
__device__ __forceinline__ ushort f2bf(float f){
    uint u = __builtin_bit_cast(uint, f);
    u += 0x7fffu + ((u >> 16) & 1u);   // round-to-nearest-even
    return (ushort)(u >> 16);
}

// ---- 0. cast feats to bf16 rows (64 wide) ----
__global__ void k_cast(const float* __restrict__ feats, ushort* __restrict__ Hx){
    int i = blockIdx.x * 256 + threadIdx.x;   // float4 groups
    if (i < N_NODES * 16){
        float4v v = ((const float4v*)feats)[i];
        short4v o;
        o[0] = (short)f2bf(v[0]); o[1] = (short)f2bf(v[1]);
        o[2] = (short)f2bf(v[2]); o[3] = (short)f2bf(v[3]);
        ((short4v*)Hx)[i] = o;
    }
}

// ---- 1. degree histogram (dst) + per-edge rank ----
__global__ void k_deg(const int* __restrict__ dst, int* __restrict__ deg,
                      int* __restrict__ rank){
    int e = blockIdx.x * 256 + threadIdx.x;
    if (e < N_EDGES) rank[e] = atomicAdd(&deg[dst[e]], 1);
}

// ---- 2. per-node CSR base (block scan + 1 atomic/block), norm ----
__global__ void k_rowptr(const int* __restrict__ deg, int* __restrict__ rowptr,
                         float* __restrict__ nrm, int* __restrict__ counter){
    __shared__ int sc[256];
    __shared__ int sbase;
    int t = threadIdx.x;
    int n = blockIdx.x * 256 + t;
    int d = (n < N_NODES) ? deg[n] : 0;
    sc[t] = d; __syncthreads();
    for (int off = 1; off < 256; off <<= 1){
        int v = 0;
        if (t >= off) v = sc[t - off];
        __syncthreads();
        sc[t] += v;
        __syncthreads();
    }
    int incl = sc[t];
    int total = sc[255];
    int excl = incl - d;
    if (t == 0) sbase = atomicAdd(counter, total);
    __syncthreads();
    if (n < N_NODES){
        rowptr[n] = sbase + excl;
        nrm[n] = rsqrtf((float)(d > 0 ? d : 1));
    }
}

// ---- 3. scatter edges into CSR (no atomic: rank precomputed) ----
__global__ void k_scatter(const int* __restrict__ src, const int* __restrict__ dst,
                          const int* __restrict__ rowptr, const int* __restrict__ rank,
                          int* __restrict__ csr){
    int e = blockIdx.x * 256 + threadIdx.x;
    if (e < N_EDGES)
        csr[rowptr[dst[e]] + rank[e]] = src[e];
}

// ---- 4. aggregation round (bf16 in, bf16 out) ----
__global__ void k_agg(const ushort* __restrict__ inp, long istride,
                      ushort* __restrict__ H, int outoff,
                      const int* __restrict__ rowptr, const int* __restrict__ deg,
                      const float* __restrict__ nrm, const int* __restrict__ csr){
    int node = (blockIdx.x << 2) + (threadIdx.x >> 6);
    int lane = threadIdx.x & 63;
    if (node >= N_NODES) return;
    int beg = rowptr[node];
    int d   = deg[node];
    float acc = 0.f;
    int i = 0;
    for (; i + 4 <= d; i += 4){
        int s0 = csr[beg+i+0], s1 = csr[beg+i+1], s2 = csr[beg+i+2], s3 = csr[beg+i+3];
        float v0 = bf2f(inp[(long)s0*istride + lane]);
        float v1 = bf2f(inp[(long)s1*istride + lane]);
        float v2 = bf2f(inp[(long)s2*istride + lane]);
        float v3 = bf2f(inp[(long)s3*istride + lane]);
        float w0 = nrm[s0], w1 = nrm[s1], w2 = nrm[s2], w3 = nrm[s3];
        acc += w0*v0; acc += w1*v1; acc += w2*v2; acc += w3*v3;
    }
    for (; i < d; ++i){
        int s = csr[beg+i];
        acc += nrm[s] * bf2f(inp[(long)s*istride + lane]);
    }
    H[(long)node*KDIM + outoff + lane] = f2bf(nrm[node] * acc);
}

// ---- 5. fold weights: MT[c][64j+d] = sum_k Wj[k,d] * fcW[c, 512j+k] ----
__global__ void k_prepM(const float* __restrict__ W0, const float* __restrict__ W1,
                        const float* __restrict__ W2, const float* __restrict__ fcW,
                        ushort* __restrict__ MT){
    int c  = blockIdx.x;        // 0..511
    int jd = threadIdx.x;       // 0..191
    int j = jd >> 6, d = jd & 63;
    const float* W  = (j == 0) ? W0 : (j == 1) ? W1 : W2;
    const float* fw = fcW + (long)c*1536 + j*512;
    float s = 0.f;
    #pragma unroll 4
    for (int k = 0; k < 512; ++k) s += W[k*64 + d] * fw[k];
    MT[c*KDIM + jd] = f2bf(s);
}

// ---- 5b. folded bias ----
__global__ void k_bias(const float* __restrict__ b0, const float* __restrict__ b1,
                       const float* __restrict__ b2, const float* __restrict__ fcW,
                       const float* __restrict__ fcb, float* __restrict__ Bc){
    int c = blockIdx.x*256 + threadIdx.x;
    if (c >= HIDDEN) return;
    const float* fw = fcW + (long)c*1536;
    float s = fcb[c];
    for (int k = 0; k < 512; ++k)
        s += b0[k]*fw[k] + b1[k]*fw[512+k] + b2[k]*fw[1024+k];
    Bc[c] = s;
}

// ---- 6. column sums of H (for mean) ----
__global__ void k_colsum(const ushort* __restrict__ H, float* __restrict__ msum){
    int t = threadIdx.x;  // 0..191
    int r0 = blockIdx.x * 391;
    int rend = min(r0 + 391, N_NODES);
    float s = 0.f;
    for (int r = r0; r < rend; ++r) s += bf2f(H[(long)r*KDIM + t]);
    atomicAdd(&msum[t], s);
}

// ---- 7. S = H^T H partials via MFMA, one 128-node chunk per block ----
// Ts[d][n_pair] as uints (lo=even node, hi=odd), bank-swizzled by (d>>2)&15
__global__ __launch_bounds__(256, 3) void k_hth(const ushort* __restrict__ H,
                                                ushort* __restrict__ P){
    __shared__ uint Ts[KDIM*64];
    int t = threadIdx.x;
    int w = t >> 6, lane = t & 63;
    int m16 = lane & 15, quad = lane >> 4;
    int mband = w * 48;
    float4v acc[3][12] = {};
    int n0 = blockIdx.x * 128;
    #pragma unroll
    for (int pd = 0; pd < 3; ++pd){
        #pragma unroll
        for (int pn = 0; pn < 4; ++pn){
            int rp = (t >> 4) + pn*16;      // row-pair 0..63
            int d4 = pd*64 + (t & 15)*4;
            int gr = n0 + rp*2;
            short4v a = {0,0,0,0}, b = {0,0,0,0};
            if (gr < N_NODES)   a = *(const short4v*)(H + (long)gr*KDIM + d4);
            if (gr+1 < N_NODES) b = *(const short4v*)(H + (long)(gr+1)*KDIM + d4);
            int g = rp >> 2, wsl = rp & 3;
            #pragma unroll
            for (int j = 0; j < 4; ++j){
                int d = d4 + j;
                uint val = (uint)(ushort)a[j] | ((uint)(ushort)b[j] << 16);
                Ts[d*64 + (((g ^ ((d>>2)&15)) << 2) | wsl)] = val;
            }
        }
    }
    __syncthreads();
    #pragma unroll
    for (int kk = 0; kk < 128; kk += 32){
        int col4 = (kk >> 3) + quad;
        short8 af[3], bf[12];
        #pragma unroll
        for (int i = 0; i < 3; ++i){
            int d = mband + i*16 + m16;
            af[i] = *(const short8*)(Ts + d*64 + ((col4 ^ ((d>>2)&15)) << 2));
        }
        #pragma unroll
        for (int j = 0; j < 12; ++j){
            int d = j*16 + m16;
            bf[j] = *(const short8*)(Ts + d*64 + ((col4 ^ ((d>>2)&15)) << 2));
        }
        #pragma unroll
        for (int i = 0; i < 3; ++i)
            #pragma unroll
            for (int j = 0; j < 12; ++j)
                acc[i][j] = __builtin_amdgcn_mfma_f32_16x16x32_bf16(af[i], bf[j], acc[i][j], 0,0,0);
    }
    ushort* Pb = P + (long)blockIdx.x * SDIM;
    #pragma unroll
    for (int i = 0; i < 3; ++i)
        #pragma unroll
        for (int j = 0; j < 12; ++j)
            #pragma unroll
            for (int r = 0; r < 4; ++r){
                int m = mband + i*16 + quad*4 + r;
                int n = j*16 + m16;
                Pb[m*KDIM + n] = f2bf(acc[i][j][r]);
            }
}

// ---- 8. reduce partials -> covariance C = S/N - mean mean^T ----
__global__ void k_reduce(const ushort* __restrict__ P, const float* __restrict__ msum,
                         float* __restrict__ C){
    int e = blockIdx.x * 256 + threadIdx.x;
    if (e >= SDIM) return;
    float s = 0.f;
    for (int b = 0; b < NCHUNK; ++b) s += bf2f(P[(long)b*SDIM + e]);
    int d = e / KDIM, dp = e - d*KDIM;
    const float invN = 1.f / (float)N_NODES;
    C[e] = s*invN - (msum[d]*invN)*(msum[dp]*invN);
}

// ---- 9. V[c] = C @ M_c  (uses symmetry of C for coalesced reads) ----
__global__ void k_cv(const float* __restrict__ C, const ushort* __restrict__ MT,
                     float* __restrict__ V){
    int c = blockIdx.x, d = threadIdx.x;  // 512 x 192
    const ushort* mt = MT + c*KDIM;
    float s = 0.f;
    #pragma unroll 4
    for (int dp = 0; dp < KDIM; ++dp)
        s += bf2f(mt[dp]) * C[dp*KDIM + d];
    V[c*KDIM + d] = s;
}

// ---- 10. BN solve: r_c, cvec ----
__global__ void k_solve2(const float* __restrict__ V, const ushort* __restrict__ MT,
                         const float* __restrict__ msum, const float* __restrict__ Bc,
                         const float* __restrict__ gamma, const float* __restrict__ beta,
                         const float* __restrict__ q,
                         float* __restrict__ rr, float* __restrict__ cvec){
    __shared__ float tmp[HIDDEN];
    int c = threadIdx.x;  // 0..511
    const float invN = 1.f / (float)N_NODES;
    float mu = Bc[c], var = 0.f;
    const ushort* mt = MT + c*KDIM;
    const float* vc = V + c*KDIM;
    #pragma unroll 4
    for (int d = 0; d < KDIM; ++d){
        float m = bf2f(mt[d]);
        mu  += msum[d]*invN * m;
        var += vc[d] * m;
    }
    float r = gamma[c] * rsqrtf(var + 1e-5f);
    rr[c] = r;
    tmp[c] = r * (Bc[c] - mu) + beta[c];
    __syncthreads();
    if (c < 64){
        float s = 0.f;
        #pragma unroll
        for (int k = 0; k < 8; ++k) s += q[k] * tmp[k*64 + c];
        cvec[c] = s;
    }
}

// ---- 11. fold rho into M: GT[o][d] = sum_k q_k r_{k64+o} MT[k64+o][d] ----
__global__ void k_buildG(const ushort* __restrict__ MT, const float* __restrict__ rr,
                         const float* __restrict__ q, ushort* __restrict__ GT){
    int o = blockIdx.x, d = threadIdx.x;  // 64 x 192
    float s = 0.f;
    #pragma unroll
    for (int k = 0; k < 8; ++k)
        s += q[k] * rr[k*64 + o] * bf2f(MT[(k*64 + o)*KDIM + d]);
    GT[o*KDIM + d] = f2bf(s);
}

// ---- 12. out = H @ GT^T + cvec ----
#define LDA 200
__global__ __launch_bounds__(256) void k_outgemm(const ushort* __restrict__ H,
                                                 const ushort* __restrict__ GT,
                                                 const float* __restrict__ cvec,
                                                 float* __restrict__ out){
    __shared__ ushort As[128*LDA];
    __shared__ ushort Gs[64*LDA];
    int t = threadIdx.x;
    int n0 = blockIdx.x * 128;
    int w = t >> 6, lane = t & 63;
    int m16 = lane & 15, quad = lane >> 4;
    int wr = w * 32;
    float4v acc[2][4] = {};
    #pragma unroll
    for (int it = 0; it < 12; ++it){
        int flat = it*256 + t;               // 0..3071 = 128 rows * 24 segs
        int row = flat / 24, seg = flat - row*24;
        int gr = n0 + row;
        short8 v = {0,0,0,0,0,0,0,0};
        if (gr < N_NODES) v = *(const short8*)(H + (long)gr*KDIM + seg*8);
        *(short8*)(As + row*LDA + seg*8) = v;
    }
    #pragma unroll
    for (int it = 0; it < 6; ++it){
        int flat = it*256 + t;               // 0..1535 = 64 rows * 24 segs
        int row = flat / 24, seg = flat - row*24;
        short8 v = *(const short8*)(GT + row*KDIM + seg*8);
        *(short8*)(Gs + row*LDA + seg*8) = v;
    }
    __syncthreads();
    #pragma unroll
    for (int kk = 0; kk < 192; kk += 32){
        short8 af[2], bf[4];
        #pragma unroll
        for (int i = 0; i < 2; ++i)
            af[i] = *(const short8*)(As + (wr + i*16 + m16)*LDA + kk + quad*8);
        #pragma unroll
        for (int j = 0; j < 4; ++j)
            bf[j] = *(const short8*)(Gs + (j*16 + m16)*LDA + kk + quad*8);
        #pragma unroll
        for (int i = 0; i < 2; ++i)
            #pragma unroll
            for (int j = 0; j < 4; ++j)
                acc[i][j] = __builtin_amdgcn_mfma_f32_16x16x32_bf16(af[i], bf[j], acc[i][j], 0,0,0);
    }
    #pragma unroll
    for (int i = 0; i < 2; ++i)
        #pragma unroll
        for (int j = 0; j < 4; ++j)
            #pragma unroll
            for (int r = 0; r < 4; ++r){
                int rowg = n0 + wr + i*16 + quad*4 + r;
                int o = j*16 + m16;
                if (rowg < N_NODES) out[(long)rowg*64 + o] = acc[i][j][r] + cvec[o];
            }
}

extern "C" void kernel_launch(void* const* d_in, const int* in_sizes, int n_in,
                              void* d_out, int out_size, void* d_ws, size_t ws_size,
                              hipStream_t stream) {
    const float* feats = (const float*)d_in[0];
    const int*   src   = (const int*)  d_in[1];
    const int*   dst   = (const int*)  d_in[2];
    const float* W0    = (const float*)d_in[3];
    const float* b0    = (const float*)d_in[4];
    const float* W1    = (const float*)d_in[5];
    const float* b1    = (const float*)d_in[6];
    const float* W2    = (const float*)d_in[7];
    const float* b2    = (const float*)d_in[8];
    const float* fcW   = (const float*)d_in[9];
    const float* fcb   = (const float*)d_in[10];
    const float* gamma = (const float*)d_in[11];
    const float* beta  = (const float*)d_in[12];
    const float* q     = (const float*)d_in[13];
    float* out = (float*)d_out;

    char* ws = (char*)d_ws;
    size_t off = 0;
    auto alloc = [&](size_t bytes) -> char* {
        char* p = ws + off;
        off = (off + bytes + 511) & ~(size_t)511;
        return p;
    };
    int*    deg     = (int*)   alloc((size_t)N_NODES * 4);
    int*    rowptr  = (int*)   alloc((size_t)N_NODES * 4);
    float*  nrm     = (float*) alloc((size_t)N_NODES * 4);
    int*    counter = (int*)   alloc(256);
    int*    rank    = (int*)   alloc((size_t)N_EDGES * 4);
    int*    csr     = (int*)   alloc((size_t)N_EDGES * 4);
    ushort* Hx      = (ushort*)alloc((size_t)N_NODES * 64 * 2);
    ushort* H       = (ushort*)alloc((size_t)N_NODES * KDIM * 2);
    ushort* MT      = (ushort*)alloc((size_t)HIDDEN * KDIM * 2);
    float*  Bc      = (float*) alloc((size_t)HIDDEN * 4);
    float*  msum    = (float*) alloc((size_t)KDIM * 4);
    ushort* P       = (ushort*)alloc((size_t)NCHUNK * SDIM * 2);
    float*  C       = (float*) alloc((size_t)SDIM * 4);
    float*  V       = (float*) alloc((size_t)HIDDEN * KDIM * 4);
    float*  rr      = (float*) alloc((size_t)HIDDEN * 4);
    float*  cvec    = (float*) alloc((size_t)64 * 4);
    ushort* GT      = (ushort*)alloc((size_t)64 * KDIM * 2);
    (void)ws_size; (void)n_in; (void)in_sizes; (void)out_size;

    hipMemsetAsync(deg, 0, (size_t)N_NODES * 4, stream);
    hipMemsetAsync(counter, 0, 4, stream);
    hipMemsetAsync(msum, 0, (size_t)KDIM * 4, stream);

    k_cast   <<<(N_NODES*16 + 255)/256, 256, 0, stream>>>(feats, Hx);
    k_deg    <<<(N_EDGES + 255)/256, 256, 0, stream>>>(dst, deg, rank);
    k_rowptr <<<(N_NODES + 255)/256, 256, 0, stream>>>(deg, rowptr, nrm, counter);
    k_scatter<<<(N_EDGES + 255)/256, 256, 0, stream>>>(src, dst, rowptr, rank, csr);

    int aggGrid = (N_NODES + 3) / 4;
    k_agg<<<aggGrid, 256, 0, stream>>>(Hx,    64,  H, 0,   rowptr, deg, nrm, csr);
    k_agg<<<aggGrid, 256, 0, stream>>>(H,     192, H, 64,  rowptr, deg, nrm, csr);
    k_agg<<<aggGrid, 256, 0, stream>>>(H+64,  192, H, 128, rowptr, deg, nrm, csr);

    k_prepM<<<HIDDEN, KDIM, 0, stream>>>(W0, W1, W2, fcW, MT);
    k_bias <<<2, 256, 0, stream>>>(b0, b1, b2, fcW, fcb, Bc);

    k_colsum<<<256, KDIM, 0, stream>>>(H, msum);
    k_hth   <<<NCHUNK, 256, 0, stream>>>(H, P);
    k_reduce<<<(SDIM + 255)/256, 256, 0, stream>>>(P, msum, C);
    k_cv    <<<HIDDEN, KDIM, 0, stream>>>(C, MT, V);
    k_solve2<<<1, HIDDEN, 0, stream>>>(V, MT, msum, Bc, gamma, beta, q, rr, cvec);
    k_buildG<<<64, KDIM, 0, stream>>>(MT, rr, q, GT);

    k_outgemm<<<NCHUNK, 256, 0, stream>>>(H, GT, cvec, out);
}

// Round 4
// 708.978 us; speedup vs baseline: 1.2816x; 1.2816x over previous
//
#include <hip/hip_runtime.h>
#include <hip/hip_bf16.h>
#include <stdint.h>

typedef unsigned short ushort;
typedef unsigned int uint;

#define N_NODES 100000
#define N_EDGES 1600000
#define KDIM 192      // 3 * 64 concatenated h_j
#define HIDDEN 512
#define NCHUNK 782    // ceil(N/128)
#define SDIM (KDIM*KDIM)
#define PSLOTS 18432  // SDIM/2 packed uints per chunk partial
#define NSPLIT 8

typedef __attribute__((ext_vector_type(8))) short short8;
typedef __attribute__((ext_vector_type(4))) short short4v;
typedef __attribute__((ext_vector_type(4))) float float4v;
typedef __attribute__((ext_vector_type(2))) float float2v;

__device__ __forceinline__ float bf2f(ushort u){
    uint x = ((uint)u) << 16;
    return __builtin_bit_cast(float, x);
}
__device__ __forceinline__ ushort f2bf(float f){
    uint u = __builtin_bit_cast(uint, f);
    u += 0x7fffu + ((u >> 16) & 1u);   // round-to-nearest-even
    return (ushort)(u >> 16);
}

// ---- 1. degree histogram (dst) + per-edge rank ----
__global__ void k_deg(const int* __restrict__ dst, int* __restrict__ deg,
                      int* __restrict__ rank){
    int e = blockIdx.x * 256 + threadIdx.x;
    if (e < N_EDGES) rank[e] = atomicAdd(&deg[dst[e]], 1);
}

// ---- 2. per-node CSR base (block scan + 1 atomic/block), norm ----
__global__ void k_rowptr(const int* __restrict__ deg, int* __restrict__ rowptr,
                         float* __restrict__ nrm, int* __restrict__ counter){
    __shared__ int sc[256];
    __shared__ int sbase;
    int t = threadIdx.x;
    int n = blockIdx.x * 256 + t;
    int d = (n < N_NODES) ? deg[n] : 0;
    sc[t] = d; __syncthreads();
    for (int off = 1; off < 256; off <<= 1){
        int v = 0;
        if (t >= off) v = sc[t - off];
        __syncthreads();
        sc[t] += v;
        __syncthreads();
    }
    int incl = sc[t];
    int total = sc[255];
    int excl = incl - d;
    if (t == 0) sbase = atomicAdd(counter, total);
    __syncthreads();
    if (n < N_NODES){
        rowptr[n] = sbase + excl;
        nrm[n] = rsqrtf((float)(d > 0 ? d : 1));
    }
}

// ---- 3. cast feats to bf16 pre-scaled by nrm: Hx = bf16(nrm .* feats) ----
__global__ void k_cast(const float* __restrict__ feats, const float* __restrict__ nrm,
                       ushort* __restrict__ Hx){
    int i = blockIdx.x * 256 + threadIdx.x;   // float4 groups, 16 per node
    if (i < N_NODES * 16){
        float w = nrm[i >> 4];
        float4v v = ((const float4v*)feats)[i];
        short4v o;
        o[0] = (short)f2bf(v[0]*w); o[1] = (short)f2bf(v[1]*w);
        o[2] = (short)f2bf(v[2]*w); o[3] = (short)f2bf(v[3]*w);
        ((short4v*)Hx)[i] = o;
    }
}

// ---- 4. scatter edges into CSR (no atomic: rank precomputed) ----
__global__ void k_scatter(const int* __restrict__ src, const int* __restrict__ dst,
                          const int* __restrict__ rowptr, const int* __restrict__ rank,
                          int* __restrict__ csr){
    int e = blockIdx.x * 256 + threadIdx.x;
    if (e < N_EDGES)
        csr[rowptr[dst[e]] + rank[e]] = src[e];
}

// ---- 5. aggregation: gather pre-scaled rows, 2 edges per wave-load ----
// input rows are 64 bf16 (=128B); lane = feature pair, half-wave = edge slot
template<bool WRITE_HS>
__global__ void k_agg(const ushort* __restrict__ inp,
                      ushort* __restrict__ H, int outoff,
                      ushort* __restrict__ Hs,
                      const int* __restrict__ rowptr, const int* __restrict__ deg,
                      const float* __restrict__ nrm, const int* __restrict__ csr){
    int node = (blockIdx.x << 2) + (threadIdx.x >> 6);
    int lane = threadIdx.x & 63;
    if (node >= N_NODES) return;
    int half = lane >> 5;          // 0/1: which edge of the pair
    int lf   = lane & 31;          // feature pair index
    int beg = rowptr[node];
    int d   = deg[node];
    float acc0 = 0.f, acc1 = 0.f;
    int i = 0;
    for (; i + 4 <= d; i += 4){
        int sA = csr[beg + i + half];
        int sB = csr[beg + i + 2 + half];
        uint vA = *(const uint*)(inp + (long)sA*64 + (lf<<1));
        uint vB = *(const uint*)(inp + (long)sB*64 + (lf<<1));
        acc0 += bf2f((ushort)vA); acc1 += bf2f((ushort)(vA>>16));
        acc0 += bf2f((ushort)vB); acc1 += bf2f((ushort)(vB>>16));
    }
    if (i + 2 <= d){
        int sA = csr[beg + i + half];
        uint vA = *(const uint*)(inp + (long)sA*64 + (lf<<1));
        acc0 += bf2f((ushort)vA); acc1 += bf2f((ushort)(vA>>16));
        i += 2;
    }
    if (i < d && half == 0){
        int sA = csr[beg + i];
        uint vA = *(const uint*)(inp + (long)sA*64 + (lf<<1));
        acc0 += bf2f((ushort)vA); acc1 += bf2f((ushort)(vA>>16));
    }
    acc0 += __shfl_xor(acc0, 32);
    acc1 += __shfl_xor(acc1, 32);
    if (half == 0){
        float wn = nrm[node];
        float a0 = wn*acc0, a1 = wn*acc1;
        *(uint*)(H + (long)node*KDIM + outoff + (lf<<1)) =
            (uint)f2bf(a0) | ((uint)f2bf(a1) << 16);
        if (WRITE_HS){
            float w2 = wn*wn;
            *(uint*)(Hs + (long)node*64 + (lf<<1)) =
                (uint)f2bf(w2*acc0) | ((uint)f2bf(w2*acc1) << 16);
        }
    }
}

// ---- 6. fold weights: MT[c][64j+d] = sum_k Wj[k,d] * fcW[c, 512j+k] ----
__global__ void k_prepM(const float* __restrict__ W0, const float* __restrict__ W1,
                        const float* __restrict__ W2, const float* __restrict__ fcW,
                        ushort* __restrict__ MT){
    int c  = blockIdx.x;        // 0..511
    int jd = threadIdx.x;       // 0..191
    int j = jd >> 6, d = jd & 63;
    const float* W  = (j == 0) ? W0 : (j == 1) ? W1 : W2;
    const float* fw = fcW + (long)c*1536 + j*512;
    float s = 0.f;
    #pragma unroll 4
    for (int k = 0; k < 512; ++k) s += W[k*64 + d] * fw[k];
    MT[c*KDIM + jd] = f2bf(s);
}

// ---- 6b. folded bias ----
__global__ void k_bias(const float* __restrict__ b0, const float* __restrict__ b1,
                       const float* __restrict__ b2, const float* __restrict__ fcW,
                       const float* __restrict__ fcb, float* __restrict__ Bc){
    int c = blockIdx.x*256 + threadIdx.x;
    if (c >= HIDDEN) return;
    const float* fw = fcW + (long)c*1536;
    float s = fcb[c];
    for (int k = 0; k < 512; ++k)
        s += b0[k]*fw[k] + b1[k]*fw[512+k] + b2[k]*fw[1024+k];
    Bc[c] = s;
}

// ---- 7. S = H^T H partials via MFMA, one 128-node chunk per block ----
// Stores partials in fragment-linear packed-bf16 layout:
//   P[b*PSLOTS + ((i*12+j)*2+rh)*256 + tid] = pack(acc[2rh], acc[2rh+1])
// Also folds column sums of H (from the transposed LDS tile) into msum.
__global__ __launch_bounds__(256, 3) void k_hth(const ushort* __restrict__ H,
                                                uint* __restrict__ P,
                                                float* __restrict__ msum){
    __shared__ uint Ts[KDIM*64];
    int t = threadIdx.x;
    int w = t >> 6, lane = t & 63;
    int m16 = lane & 15, quad = lane >> 4;
    int mband = w * 48;
    float4v acc[3][12] = {};
    int n0 = blockIdx.x * 128;
    #pragma unroll
    for (int pd = 0; pd < 3; ++pd){
        #pragma unroll
        for (int pn = 0; pn < 4; ++pn){
            int rp = (t >> 4) + pn*16;      // row-pair 0..63
            int d4 = pd*64 + (t & 15)*4;
            int gr = n0 + rp*2;
            short4v a = {0,0,0,0}, b = {0,0,0,0};
            if (gr < N_NODES)   a = *(const short4v*)(H + (long)gr*KDIM + d4);
            if (gr+1 < N_NODES) b = *(const short4v*)(H + (long)(gr+1)*KDIM + d4);
            int g = rp >> 2, wsl = rp & 3;
            #pragma unroll
            for (int j = 0; j < 4; ++j){
                int d = d4 + j;
                uint val = (uint)(ushort)a[j] | ((uint)(ushort)b[j] << 16);
                Ts[d*64 + (((g ^ ((d>>2)&15)) << 2) | wsl)] = val;
            }
        }
    }
    __syncthreads();
    #pragma unroll
    for (int kk = 0; kk < 128; kk += 32){
        int col4 = (kk >> 3) + quad;
        short8 af[3], bf[12];
        #pragma unroll
        for (int i = 0; i < 3; ++i){
            int d = mband + i*16 + m16;
            af[i] = *(const short8*)(Ts + d*64 + ((col4 ^ ((d>>2)&15)) << 2));
        }
        #pragma unroll
        for (int j = 0; j < 12; ++j){
            int d = j*16 + m16;
            bf[j] = *(const short8*)(Ts + d*64 + ((col4 ^ ((d>>2)&15)) << 2));
        }
        #pragma unroll
        for (int i = 0; i < 3; ++i)
            #pragma unroll
            for (int j = 0; j < 12; ++j)
                acc[i][j] = __builtin_amdgcn_mfma_f32_16x16x32_bf16(af[i], bf[j], acc[i][j], 0,0,0);
    }
    // folded column sums (Ts only read after this point's prior sync)
    if (t < KDIM){
        float s = 0.f;
        #pragma unroll 8
        for (int x = 0; x < 64; ++x){
            uint v = Ts[t*64 + x];
            s += bf2f((ushort)(v & 0xffff)) + bf2f((ushort)(v >> 16));
        }
        atomicAdd(&msum[t], s);
    }
    uint* Pb = P + (long)blockIdx.x * PSLOTS;
    #pragma unroll
    for (int i = 0; i < 3; ++i)
        #pragma unroll
        for (int j = 0; j < 12; ++j)
            #pragma unroll
            for (int rh = 0; rh < 2; ++rh){
                uint v = (uint)f2bf(acc[i][j][2*rh]) | ((uint)f2bf(acc[i][j][2*rh+1]) << 16);
                Pb[((i*12 + j)*2 + rh)*256 + t] = v;
            }
}

// ---- 8. split-K reduce of partials (coalesced) ----
__global__ void k_reduce(const uint* __restrict__ P, float* __restrict__ SP){
    int p = blockIdx.x * 256 + threadIdx.x;   // 0..18431
    int y = blockIdx.y;
    int b0 = y * 98, b1 = min(b0 + 98, NCHUNK);
    float lo = 0.f, hi = 0.f;
    for (int b = b0; b < b1; ++b){
        uint v = P[(long)b*PSLOTS + p];
        lo += bf2f((ushort)(v & 0xffff));
        hi += bf2f((ushort)(v >> 16));
    }
    float2v o; o[0] = lo; o[1] = hi;
    *(float2v*)(SP + (long)y*SDIM + p*2) = o;
}

// ---- 9. finalize covariance C = S/N - mean mean^T (un-permute fragment layout) ----
__global__ void k_finC(const float* __restrict__ SP, const float* __restrict__ msum,
                       float* __restrict__ C){
    int idx = blockIdx.x * 256 + threadIdx.x;   // 0..36863
    float s = 0.f;
    #pragma unroll
    for (int y = 0; y < NSPLIT; ++y) s += SP[(long)y*SDIM + idx];
    int h = idx & 1, p = idx >> 1;
    int t0 = p & 255, slot = p >> 8;
    int ii = slot / 24, rem = slot - ii*24;
    int j = rem >> 1, rh = rem & 1, r = rh*2 + h;
    int w = t0 >> 6, lane = t0 & 63;
    int quad = lane >> 4, m16 = lane & 15;
    int m = w*48 + ii*16 + quad*4 + r;
    int n = j*16 + m16;
    const float invN = 1.f / (float)N_NODES;
    C[m*KDIM + n] = s*invN - (msum[m]*invN)*(msum[n]*invN);
}

// ---- 10. V[c] = C @ M_c ----
__global__ void k_cv(const float* __restrict__ C, const ushort* __restrict__ MT,
                     float* __restrict__ V){
    int c = blockIdx.x, d = threadIdx.x;  // 512 x 192
    const ushort* mt = MT + c*KDIM;
    float s = 0.f;
    #pragma unroll 4
    for (int dp = 0; dp < KDIM; ++dp)
        s += bf2f(mt[dp]) * C[dp*KDIM + d];
    V[c*KDIM + d] = s;
}

// ---- 11. BN solve: r_c, cvec ----
__global__ void k_solve2(const float* __restrict__ V, const ushort* __restrict__ MT,
                         const float* __restrict__ msum, const float* __restrict__ Bc,
                         const float* __restrict__ gamma, const float* __restrict__ beta,
                         const float* __restrict__ q,
                         float* __restrict__ rr, float* __restrict__ cvec){
    __shared__ float tmp[HIDDEN];
    int c = threadIdx.x;  // 0..511
    const float invN = 1.f / (float)N_NODES;
    float mu = Bc[c], var = 0.f;
    const ushort* mt = MT + c*KDIM;
    const float* vc = V + c*KDIM;
    #pragma unroll 4
    for (int d = 0; d < KDIM; ++d){
        float m = bf2f(mt[d]);
        mu  += msum[d]*invN * m;
        var += vc[d] * m;
    }
    float r = gamma[c] * rsqrtf(var + 1e-5f);
    rr[c] = r;
    tmp[c] = r * (Bc[c] - mu) + beta[c];
    __syncthreads();
    if (c < 64){
        float s = 0.f;
        #pragma unroll
        for (int k = 0; k < 8; ++k) s += q[k] * tmp[k*64 + c];
        cvec[c] = s;
    }
}

// ---- 12. fold rho into M: GT[o][d] = sum_k q_k r_{k64+o} MT[k64+o][d] ----
__global__ void k_buildG(const ushort* __restrict__ MT, const float* __restrict__ rr,
                         const float* __restrict__ q, ushort* __restrict__ GT){
    int o = blockIdx.x, d = threadIdx.x;  // 64 x 192
    float s = 0.f;
    #pragma unroll
    for (int k = 0; k < 8; ++k)
        s += q[k] * rr[k*64 + o] * bf2f(MT[(k*64 + o)*KDIM + d]);
    GT[o*KDIM + d] = f2bf(s);
}

// ---- 13. out = H @ GT^T + cvec ----
#define LDA 200
__global__ __launch_bounds__(256) void k_outgemm(const ushort* __restrict__ H,
                                                 const ushort* __restrict__ GT,
                                                 const float* __restrict__ cvec,
                                                 float* __restrict__ out){
    __shared__ ushort As[128*LDA];
    __shared__ ushort Gs[64*LDA];
    int t = threadIdx.x;
    int n0 = blockIdx.x * 128;
    int w = t >> 6, lane = t & 63;
    int m16 = lane & 15, quad = lane >> 4;
    int wr = w * 32;
    float4v acc[2][4] = {};
    #pragma unroll
    for (int it = 0; it < 12; ++it){
        int flat = it*256 + t;               // 0..3071 = 128 rows * 24 segs
        int row = flat / 24, seg = flat - row*24;
        int gr = n0 + row;
        short8 v = {0,0,0,0,0,0,0,0};
        if (gr < N_NODES) v = *(const short8*)(H + (long)gr*KDIM + seg*8);
        *(short8*)(As + row*LDA + seg*8) = v;
    }
    #pragma unroll
    for (int it = 0; it < 6; ++it){
        int flat = it*256 + t;               // 0..1535 = 64 rows * 24 segs
        int row = flat / 24, seg = flat - row*24;
        short8 v = *(const short8*)(GT + row*KDIM + seg*8);
        *(short8*)(Gs + row*LDA + seg*8) = v;
    }
    __syncthreads();
    #pragma unroll
    for (int kk = 0; kk < 192; kk += 32){
        short8 af[2], bf[4];
        #pragma unroll
        for (int i = 0; i < 2; ++i)
            af[i] = *(const short8*)(As + (wr + i*16 + m16)*LDA + kk + quad*8);
        #pragma unroll
        for (int j = 0; j < 4; ++j)
            bf[j] = *(const short8*)(Gs + (j*16 + m16)*LDA + kk + quad*8);
        #pragma unroll
        for (int i = 0; i < 2; ++i)
            #pragma unroll
            for (int j = 0; j < 4; ++j)
                acc[i][j] = __builtin_amdgcn_mfma_f32_16x16x32_bf16(af[i], bf[j], acc[i][j], 0,0,0);
    }
    #pragma unroll
    for (int i = 0; i < 2; ++i)
        #pragma unroll
        for (int j = 0; j < 4; ++j)
            #pragma unroll
            for (int r = 0; r < 4; ++r){
                int rowg = n0 + wr + i*16 + quad*4 + r;
                int o = j*16 + m16;
                if (rowg < N_NODES) out[(long)rowg*64 + o] = acc[i][j][r] + cvec[o];
            }
}

extern "C" void kernel_launch(void* const* d_in, const int* in_sizes, int n_in,
                              void* d_out, int out_size, void* d_ws, size_t ws_size,
                              hipStream_t stream) {
    const float* feats = (const float*)d_in[0];
    const int*   src   = (const int*)  d_in[1];
    const int*   dst   = (const int*)  d_in[2];
    const float* W0    = (const float*)d_in[3];
    const float* b0    = (const float*)d_in[4];
    const float* W1    = (const float*)d_in[5];
    const float* b1    = (const float*)d_in[6];
    const float* W2    = (const float*)d_in[7];
    const float* b2    = (const float*)d_in[8];
    const float* fcW   = (const float*)d_in[9];
    const float* fcb   = (const float*)d_in[10];
    const float* gamma = (const float*)d_in[11];
    const float* beta  = (const float*)d_in[12];
    const float* q     = (const float*)d_in[13];
    float* out = (float*)d_out;

    char* ws = (char*)d_ws;
    size_t off = 0;
    auto alloc = [&](size_t bytes) -> char* {
        char* p = ws + off;
        off = (off + bytes + 511) & ~(size_t)511;
        return p;
    };
    int*    deg     = (int*)   alloc((size_t)N_NODES * 4);
    int*    rowptr  = (int*)   alloc((size_t)N_NODES * 4);
    float*  nrm     = (float*) alloc((size_t)N_NODES * 4);
    int*    counter = (int*)   alloc(256);
    int*    rank    = (int*)   alloc((size_t)N_EDGES * 4);
    int*    csr     = (int*)   alloc((size_t)N_EDGES * 4);
    ushort* Hx      = (ushort*)alloc((size_t)N_NODES * 64 * 2);
    ushort* HsB     = (ushort*)alloc((size_t)N_NODES * 64 * 2);
    ushort* H       = (ushort*)alloc((size_t)N_NODES * KDIM * 2);
    ushort* MT      = (ushort*)alloc((size_t)HIDDEN * KDIM * 2);
    float*  Bc      = (float*) alloc((size_t)HIDDEN * 4);
    float*  msum    = (float*) alloc((size_t)KDIM * 4);
    uint*   P       = (uint*)  alloc((size_t)NCHUNK * PSLOTS * 4);
    float*  SP      = (float*) alloc((size_t)NSPLIT * SDIM * 4);
    float*  C       = (float*) alloc((size_t)SDIM * 4);
    float*  V       = (float*) alloc((size_t)HIDDEN * KDIM * 4);
    float*  rr      = (float*) alloc((size_t)HIDDEN * 4);
    float*  cvec    = (float*) alloc((size_t)64 * 4);
    ushort* GT      = (ushort*)alloc((size_t)64 * KDIM * 2);
    (void)ws_size; (void)n_in; (void)in_sizes; (void)out_size;

    hipMemsetAsync(deg, 0, (size_t)N_NODES * 4, stream);
    hipMemsetAsync(counter, 0, 4, stream);
    hipMemsetAsync(msum, 0, (size_t)KDIM * 4, stream);

    k_deg    <<<(N_EDGES + 255)/256, 256, 0, stream>>>(dst, deg, rank);
    k_rowptr <<<(N_NODES + 255)/256, 256, 0, stream>>>(deg, rowptr, nrm, counter);
    k_cast   <<<(N_NODES*16 + 255)/256, 256, 0, stream>>>(feats, nrm, Hx);
    k_scatter<<<(N_EDGES + 255)/256, 256, 0, stream>>>(src, dst, rowptr, rank, csr);

    int aggGrid = (N_NODES + 3) / 4;
    k_agg<true> <<<aggGrid, 256, 0, stream>>>(Hx,  H, 0,   HsB, rowptr, deg, nrm, csr);
    k_agg<true> <<<aggGrid, 256, 0, stream>>>(HsB, H, 64,  Hx,  rowptr, deg, nrm, csr);
    k_agg<false><<<aggGrid, 256, 0, stream>>>(Hx,  H, 128, HsB, rowptr, deg, nrm, csr);

    k_prepM<<<HIDDEN, KDIM, 0, stream>>>(W0, W1, W2, fcW, MT);
    k_bias <<<2, 256, 0, stream>>>(b0, b1, b2, fcW, fcb, Bc);

    k_hth   <<<NCHUNK, 256, 0, stream>>>(H, P, msum);
    dim3 rGrid(PSLOTS/256, NSPLIT);
    k_reduce<<<rGrid, 256, 0, stream>>>(P, SP);
    k_finC  <<<SDIM/256, 256, 0, stream>>>(SP, msum, C);
    k_cv    <<<HIDDEN, KDIM, 0, stream>>>(C, MT, V);
    k_solve2<<<1, HIDDEN, 0, stream>>>(V, MT, msum, Bc, gamma, beta, q, rr, cvec);
    k_buildG<<<64, KDIM, 0, stream>>>(MT, rr, q, GT);

    k_outgemm<<<NCHUNK, 256, 0, stream>>>(H, GT, cvec, out);
}

// Round 5
// 583.583 us; speedup vs baseline: 1.5570x; 1.2149x over previous
//
#include <hip/hip_runtime.h>
#include <hip/hip_bf16.h>
#include <stdint.h>

typedef unsigned short ushort;
typedef unsigned int uint;

#define N_NODES 100000
#define N_EDGES 1600000
#define KDIM 192      // 3 * 64 concatenated h_j
#define HIDDEN 512
#define NCHUNK 782    // ceil(N/128)
#define SDIM (KDIM*KDIM)
#define NPAIR 78      // 12*13/2 upper-triangle band pairs
#define PPB   9984    // uints per block partial: 78 frags * 128 uints
#define NSPLIT 8
#define LDT 194       // ushort stride of node-major LDS tile (192 + 2 pad)

typedef __attribute__((ext_vector_type(8))) short short8;
typedef __attribute__((ext_vector_type(4))) short short4v;
typedef __attribute__((ext_vector_type(4))) float float4v;
typedef __attribute__((ext_vector_type(2))) float float2v;
typedef __attribute__((ext_vector_type(2))) uint uint2v;

__device__ __forceinline__ float bf2f(ushort u){
    uint x = ((uint)u) << 16;
    return __builtin_bit_cast(float, x);
}
__device__ __forceinline__ ushort f2bf(float f){
    uint u = __builtin_bit_cast(uint, f);
    u += 0x7fffu + ((u >> 16) & 1u);   // round-to-nearest-even
    return (ushort)(u >> 16);
}

// ---- 1. degree histogram (dst) + per-edge rank ----
__global__ void k_deg(const int* __restrict__ dst, int* __restrict__ deg,
                      int* __restrict__ rank){
    int e = blockIdx.x * 256 + threadIdx.x;
    if (e < N_EDGES) rank[e] = atomicAdd(&deg[dst[e]], 1);
}

// ---- 2. per-node CSR base (block scan + 1 atomic/block), norm ----
__global__ void k_rowptr(const int* __restrict__ deg, int* __restrict__ rowptr,
                         float* __restrict__ nrm, int* __restrict__ counter){
    __shared__ int sc[256];
    __shared__ int sbase;
    int t = threadIdx.x;
    int n = blockIdx.x * 256 + t;
    int d = (n < N_NODES) ? deg[n] : 0;
    sc[t] = d; __syncthreads();
    for (int off = 1; off < 256; off <<= 1){
        int v = 0;
        if (t >= off) v = sc[t - off];
        __syncthreads();
        sc[t] += v;
        __syncthreads();
    }
    int incl = sc[t];
    int total = sc[255];
    int excl = incl - d;
    if (t == 0) sbase = atomicAdd(counter, total);
    __syncthreads();
    if (n < N_NODES){
        rowptr[n] = sbase + excl;
        nrm[n] = rsqrtf((float)(d > 0 ? d : 1));
    }
}

// ---- 3. cast feats to bf16 pre-scaled by nrm ----
__global__ void k_cast(const float* __restrict__ feats, const float* __restrict__ nrm,
                       ushort* __restrict__ Hx){
    int i = blockIdx.x * 256 + threadIdx.x;   // float4 groups, 16 per node
    if (i < N_NODES * 16){
        float w = nrm[i >> 4];
        float4v v = ((const float4v*)feats)[i];
        short4v o;
        o[0] = (short)f2bf(v[0]*w); o[1] = (short)f2bf(v[1]*w);
        o[2] = (short)f2bf(v[2]*w); o[3] = (short)f2bf(v[3]*w);
        ((short4v*)Hx)[i] = o;
    }
}

// ---- 4. scatter edges into CSR, XCD-affine by dst region ----
// block b: region = b&7 (heuristic XCD id), slice = b>>3 of the edge array.
// Each region's ~800KB csr window stays hot in one XCD's L2.
#define SC_SLICES 256
__global__ void k_scatter(const int* __restrict__ src, const int* __restrict__ dst,
                          const int* __restrict__ rowptr, const int* __restrict__ rank,
                          int* __restrict__ csr){
    int b = blockIdx.x;
    int region = b & 7;
    int slice  = b >> 3;
    int lo = region * (N_NODES/8), hi = lo + (N_NODES/8);
    int e0 = slice * (N_EDGES/SC_SLICES);
    int e1 = e0 + (N_EDGES/SC_SLICES);
    for (int e = e0 + threadIdx.x; e < e1; e += 256){
        int d = dst[e];
        if (d >= lo && d < hi)
            csr[rowptr[d] + rank[e]] = src[e];
    }
}

// ---- 5. aggregation: gather pre-scaled rows, 2 edges per wave-load, 8-deep ----
template<bool WRITE_HS>
__global__ void k_agg(const ushort* __restrict__ inp,
                      ushort* __restrict__ H, int outoff,
                      ushort* __restrict__ Hs,
                      const int* __restrict__ rowptr, const int* __restrict__ deg,
                      const float* __restrict__ nrm, const int* __restrict__ csr){
    int node = (blockIdx.x << 2) + (threadIdx.x >> 6);
    int lane = threadIdx.x & 63;
    if (node >= N_NODES) return;
    int half = lane >> 5;          // 0/1: which edge of the pair
    int lf   = lane & 31;          // feature pair index
    int beg = rowptr[node];
    int d   = deg[node];
    float acc0 = 0.f, acc1 = 0.f;
    int i = 0;
    for (; i + 8 <= d; i += 8){
        int sA = csr[beg + i + half];
        int sB = csr[beg + i + 2 + half];
        int sC = csr[beg + i + 4 + half];
        int sD = csr[beg + i + 6 + half];
        uint vA = *(const uint*)(inp + (long)sA*64 + (lf<<1));
        uint vB = *(const uint*)(inp + (long)sB*64 + (lf<<1));
        uint vC = *(const uint*)(inp + (long)sC*64 + (lf<<1));
        uint vD = *(const uint*)(inp + (long)sD*64 + (lf<<1));
        acc0 += bf2f((ushort)vA); acc1 += bf2f((ushort)(vA>>16));
        acc0 += bf2f((ushort)vB); acc1 += bf2f((ushort)(vB>>16));
        acc0 += bf2f((ushort)vC); acc1 += bf2f((ushort)(vC>>16));
        acc0 += bf2f((ushort)vD); acc1 += bf2f((ushort)(vD>>16));
    }
    if (i + 4 <= d){
        int sA = csr[beg + i + half];
        int sB = csr[beg + i + 2 + half];
        uint vA = *(const uint*)(inp + (long)sA*64 + (lf<<1));
        uint vB = *(const uint*)(inp + (long)sB*64 + (lf<<1));
        acc0 += bf2f((ushort)vA); acc1 += bf2f((ushort)(vA>>16));
        acc0 += bf2f((ushort)vB); acc1 += bf2f((ushort)(vB>>16));
        i += 4;
    }
    if (i + 2 <= d){
        int sA = csr[beg + i + half];
        uint vA = *(const uint*)(inp + (long)sA*64 + (lf<<1));
        acc0 += bf2f((ushort)vA); acc1 += bf2f((ushort)(vA>>16));
        i += 2;
    }
    if (i < d && half == 0){
        int sA = csr[beg + i];
        uint vA = *(const uint*)(inp + (long)sA*64 + (lf<<1));
        acc0 += bf2f((ushort)vA); acc1 += bf2f((ushort)(vA>>16));
    }
    acc0 += __shfl_xor(acc0, 32);
    acc1 += __shfl_xor(acc1, 32);
    if (half == 0){
        float wn = nrm[node];
        *(uint*)(H + (long)node*KDIM + outoff + (lf<<1)) =
            (uint)f2bf(wn*acc0) | ((uint)f2bf(wn*acc1) << 16);
        if (WRITE_HS){
            float w2 = wn*wn;
            *(uint*)(Hs + (long)node*64 + (lf<<1)) =
                (uint)f2bf(w2*acc0) | ((uint)f2bf(w2*acc1) << 16);
        }
    }
}

// ---- 6. fold weights: MT[c][64j+d] = sum_k Wj[k,d] * fcW[c, 512j+k] ----
__global__ void k_prepM(const float* __restrict__ W0, const float* __restrict__ W1,
                        const float* __restrict__ W2, const float* __restrict__ fcW,
                        ushort* __restrict__ MT){
    int c  = blockIdx.x;        // 0..511
    int jd = threadIdx.x;       // 0..191
    int j = jd >> 6, d = jd & 63;
    const float* W  = (j == 0) ? W0 : (j == 1) ? W1 : W2;
    const float* fw = fcW + (long)c*1536 + j*512;
    float s = 0.f;
    #pragma unroll 4
    for (int k = 0; k < 512; ++k) s += W[k*64 + d] * fw[k];
    MT[c*KDIM + jd] = f2bf(s);
}

// ---- 6b. folded bias ----
__global__ void k_bias(const float* __restrict__ b0, const float* __restrict__ b1,
                       const float* __restrict__ b2, const float* __restrict__ fcW,
                       const float* __restrict__ fcb, float* __restrict__ Bc){
    int c = blockIdx.x*256 + threadIdx.x;
    if (c >= HIDDEN) return;
    const float* fw = fcW + (long)c*1536;
    float s = fcb[c];
    for (int k = 0; k < 512; ++k)
        s += b0[k]*fw[k] + b1[k]*fw[512+k] + b2[k]*fw[1024+k];
    Bc[c] = s;
}

// ---- 7. symmetric H^T H: node-major LDS, 78 upper-tri band pairs ----
template<int W>
__device__ __forceinline__ void do_pairs(const short8* frag, float4v* acc){
    int p = 0, c = 0;
    #pragma unroll
    for (int i = 0; i < 12; ++i)
        #pragma unroll
        for (int j = i; j < 12; ++j){
            if ((p & 3) == W){
                acc[c] = __builtin_amdgcn_mfma_f32_16x16x32_bf16(frag[i], frag[j], acc[c], 0,0,0);
                ++c;
            }
            ++p;
        }
}
template<int W>
__device__ __forceinline__ void store_pairs(const float4v* acc, uint* Pb, int lane){
    int p = 0, c = 0;
    #pragma unroll
    for (int i = 0; i < 12; ++i)
        #pragma unroll
        for (int j = i; j < 12; ++j){
            if ((p & 3) == W){
                uint2v v;
                v[0] = (uint)f2bf(acc[c][0]) | ((uint)f2bf(acc[c][1]) << 16);
                v[1] = (uint)f2bf(acc[c][2]) | ((uint)f2bf(acc[c][3]) << 16);
                *(uint2v*)(Pb + p*128 + lane*2) = v;
                ++c;
            }
            ++p;
        }
}

__global__ __launch_bounds__(256, 2) void k_hth(const ushort* __restrict__ H,
                                                uint* __restrict__ P,
                                                float* __restrict__ msum){
    __shared__ ushort Ts[128*LDT];   // 49664 B, node-major
    int t = threadIdx.x;
    int w = t >> 6, lane = t & 63;
    int m16 = lane & 15, quad = lane >> 4;
    int n0 = blockIdx.x * 128;
    #pragma unroll
    for (int it = 0; it < 12; ++it){
        int flat = it*256 + t;           // 128 rows * 24 segs
        int row = flat / 24, seg = flat - row*24;
        int gr = n0 + row;
        short8 v = {0,0,0,0,0,0,0,0};
        if (gr < N_NODES) v = *(const short8*)(H + (long)gr*KDIM + seg*8);
        *(short8*)(Ts + row*LDT + seg*8) = v;
    }
    __syncthreads();
    float4v acc[20] = {};
    #pragma unroll
    for (int kt = 0; kt < 4; ++kt){
        short8 frag[12];
        #pragma unroll
        for (int b = 0; b < 12; ++b){
            short8 f;
            #pragma unroll
            for (int j = 0; j < 8; ++j)
                f[j] = (short)Ts[(kt*32 + quad*8 + j)*LDT + b*16 + m16];
            frag[b] = f;
        }
        if      (w == 0) do_pairs<0>(frag, acc);
        else if (w == 1) do_pairs<1>(frag, acc);
        else if (w == 2) do_pairs<2>(frag, acc);
        else             do_pairs<3>(frag, acc);
    }
    // folded column sums (Ts untouched since staging)
    if (t < KDIM){
        float s = 0.f;
        #pragma unroll 4
        for (int n = 0; n < 128; ++n) s += bf2f(Ts[n*LDT + t]);
        atomicAdd(&msum[t], s);
    }
    uint* Pb = P + (long)blockIdx.x * PPB;
    if      (w == 0) store_pairs<0>(acc, Pb, lane);
    else if (w == 1) store_pairs<1>(acc, Pb, lane);
    else if (w == 2) store_pairs<2>(acc, Pb, lane);
    else             store_pairs<3>(acc, Pb, lane);
}

// ---- 8. split-K reduce of partials (coalesced) ----
__global__ void k_reduce(const uint* __restrict__ P, float* __restrict__ SP){
    int p = blockIdx.x * 256 + threadIdx.x;   // 0..9983
    int y = blockIdx.y;
    int b0 = y * 98, b1 = min(b0 + 98, NCHUNK);
    float lo = 0.f, hi = 0.f;
    for (int b = b0; b < b1; ++b){
        uint v = P[(long)b*PPB + p];
        lo += bf2f((ushort)(v & 0xffff));
        hi += bf2f((ushort)(v >> 16));
    }
    float2v o; o[0] = lo; o[1] = hi;
    *(float2v*)(SP + (long)y*(NPAIR*256) + p*2) = o;
}

// ---- 9. finalize covariance C (both triangles) from fragment layout ----
__global__ void k_finC(const float* __restrict__ SP, const float* __restrict__ msum,
                       float* __restrict__ C){
    int idx = blockIdx.x * 256 + threadIdx.x;   // 0..19967
    float s = 0.f;
    #pragma unroll
    for (int y = 0; y < NSPLIT; ++y) s += SP[(long)y*(NPAIR*256) + idx];
    int h = idx & 1, pu = idx >> 1;
    int p = pu >> 7, rem = pu & 127;
    int l = rem >> 1, u = rem & 1;
    int r = u*2 + h;
    int pi = 0, pj = 0, off = 0;
    #pragma unroll
    for (int k = 0; k < 12; ++k){
        int len = 12 - k;
        if (p >= off && p < off + len){ pi = k; pj = k + (p - off); }
        off += len;
    }
    int m = pi*16 + (l >> 4)*4 + r;
    int n = pj*16 + (l & 15);
    const float invN = 1.f / (float)N_NODES;
    float v = s*invN - (msum[m]*invN)*(msum[n]*invN);
    C[m*KDIM + n] = v;
    C[n*KDIM + m] = v;
}

// ---- 10. V[c] = C @ M_c ----
__global__ void k_cv(const float* __restrict__ C, const ushort* __restrict__ MT,
                     float* __restrict__ V){
    int c = blockIdx.x, d = threadIdx.x;  // 512 x 192
    const ushort* mt = MT + c*KDIM;
    float s = 0.f;
    #pragma unroll 4
    for (int dp = 0; dp < KDIM; ++dp)
        s += bf2f(mt[dp]) * C[dp*KDIM + d];
    V[c*KDIM + d] = s;
}

// ---- 11. BN solve: r_c, cvec ----
__global__ void k_solve2(const float* __restrict__ V, const ushort* __restrict__ MT,
                         const float* __restrict__ msum, const float* __restrict__ Bc,
                         const float* __restrict__ gamma, const float* __restrict__ beta,
                         const float* __restrict__ q,
                         float* __restrict__ rr, float* __restrict__ cvec){
    __shared__ float tmp[HIDDEN];
    int c = threadIdx.x;  // 0..511
    const float invN = 1.f / (float)N_NODES;
    float mu = Bc[c], var = 0.f;
    const ushort* mt = MT + c*KDIM;
    const float* vc = V + c*KDIM;
    #pragma unroll 4
    for (int d = 0; d < KDIM; ++d){
        float m = bf2f(mt[d]);
        mu  += msum[d]*invN * m;
        var += vc[d] * m;
    }
    float r = gamma[c] * rsqrtf(var + 1e-5f);
    rr[c] = r;
    tmp[c] = r * (Bc[c] - mu) + beta[c];
    __syncthreads();
    if (c < 64){
        float s = 0.f;
        #pragma unroll
        for (int k = 0; k < 8; ++k) s += q[k] * tmp[k*64 + c];
        cvec[c] = s;
    }
}

// ---- 12. fold rho into M: GT[o][d] = sum_k q_k r_{k64+o} MT[k64+o][d] ----
__global__ void k_buildG(const ushort* __restrict__ MT, const float* __restrict__ rr,
                         const float* __restrict__ q, ushort* __restrict__ GT){
    int o = blockIdx.x, d = threadIdx.x;  // 64 x 192
    float s = 0.f;
    #pragma unroll
    for (int k = 0; k < 8; ++k)
        s += q[k] * rr[k*64 + o] * bf2f(MT[(k*64 + o)*KDIM + d]);
    GT[o*KDIM + d] = f2bf(s);
}

// ---- 13. out = H @ GT^T + cvec ----
#define LDA 200
__global__ __launch_bounds__(256) void k_outgemm(const ushort* __restrict__ H,
                                                 const ushort* __restrict__ GT,
                                                 const float* __restrict__ cvec,
                                                 float* __restrict__ out){
    __shared__ ushort As[128*LDA];
    __shared__ ushort Gs[64*LDA];
    int t = threadIdx.x;
    int n0 = blockIdx.x * 128;
    int w = t >> 6, lane = t & 63;
    int m16 = lane & 15, quad = lane >> 4;
    int wr = w * 32;
    float4v acc[2][4] = {};
    #pragma unroll
    for (int it = 0; it < 12; ++it){
        int flat = it*256 + t;               // 128 rows * 24 segs
        int row = flat / 24, seg = flat - row*24;
        int gr = n0 + row;
        short8 v = {0,0,0,0,0,0,0,0};
        if (gr < N_NODES) v = *(const short8*)(H + (long)gr*KDIM + seg*8);
        *(short8*)(As + row*LDA + seg*8) = v;
    }
    #pragma unroll
    for (int it = 0; it < 6; ++it){
        int flat = it*256 + t;               // 64 rows * 24 segs
        int row = flat / 24, seg = flat - row*24;
        short8 v = *(const short8*)(GT + row*KDIM + seg*8);
        *(short8*)(Gs + row*LDA + seg*8) = v;
    }
    __syncthreads();
    #pragma unroll
    for (int kk = 0; kk < 192; kk += 32){
        short8 af[2], bf[4];
        #pragma unroll
        for (int i = 0; i < 2; ++i)
            af[i] = *(const short8*)(As + (wr + i*16 + m16)*LDA + kk + quad*8);
        #pragma unroll
        for (int j = 0; j < 4; ++j)
            bf[j] = *(const short8*)(Gs + (j*16 + m16)*LDA + kk + quad*8);
        #pragma unroll
        for (int i = 0; i < 2; ++i)
            #pragma unroll
            for (int j = 0; j < 4; ++j)
                acc[i][j] = __builtin_amdgcn_mfma_f32_16x16x32_bf16(af[i], bf[j], acc[i][j], 0,0,0);
    }
    #pragma unroll
    for (int i = 0; i < 2; ++i)
        #pragma unroll
        for (int j = 0; j < 4; ++j)
            #pragma unroll
            for (int r = 0; r < 4; ++r){
                int rowg = n0 + wr + i*16 + quad*4 + r;
                int o = j*16 + m16;
                if (rowg < N_NODES) out[(long)rowg*64 + o] = acc[i][j][r] + cvec[o];
            }
}

extern "C" void kernel_launch(void* const* d_in, const int* in_sizes, int n_in,
                              void* d_out, int out_size, void* d_ws, size_t ws_size,
                              hipStream_t stream) {
    const float* feats = (const float*)d_in[0];
    const int*   src   = (const int*)  d_in[1];
    const int*   dst   = (const int*)  d_in[2];
    const float* W0    = (const float*)d_in[3];
    const float* b0    = (const float*)d_in[4];
    const float* W1    = (const float*)d_in[5];
    const float* b1    = (const float*)d_in[6];
    const float* W2    = (const float*)d_in[7];
    const float* b2    = (const float*)d_in[8];
    const float* fcW   = (const float*)d_in[9];
    const float* fcb   = (const float*)d_in[10];
    const float* gamma = (const float*)d_in[11];
    const float* beta  = (const float*)d_in[12];
    const float* q     = (const float*)d_in[13];
    float* out = (float*)d_out;

    char* ws = (char*)d_ws;
    size_t off = 0;
    auto alloc = [&](size_t bytes) -> char* {
        char* p = ws + off;
        off = (off + bytes + 511) & ~(size_t)511;
        return p;
    };
    int*    deg     = (int*)   alloc((size_t)N_NODES * 4);
    int*    rowptr  = (int*)   alloc((size_t)N_NODES * 4);
    float*  nrm     = (float*) alloc((size_t)N_NODES * 4);
    int*    counter = (int*)   alloc(256);
    int*    rank    = (int*)   alloc((size_t)N_EDGES * 4);
    int*    csr     = (int*)   alloc((size_t)N_EDGES * 4);
    ushort* Hx      = (ushort*)alloc((size_t)N_NODES * 64 * 2);
    ushort* HsB     = (ushort*)alloc((size_t)N_NODES * 64 * 2);
    ushort* H       = (ushort*)alloc((size_t)N_NODES * KDIM * 2);
    ushort* MT      = (ushort*)alloc((size_t)HIDDEN * KDIM * 2);
    float*  Bc      = (float*) alloc((size_t)HIDDEN * 4);
    float*  msum    = (float*) alloc((size_t)KDIM * 4);
    uint*   P       = (uint*)  alloc((size_t)NCHUNK * PPB * 4);
    float*  SP      = (float*) alloc((size_t)NSPLIT * NPAIR * 256 * 4);
    float*  C       = (float*) alloc((size_t)SDIM * 4);
    float*  V       = (float*) alloc((size_t)HIDDEN * KDIM * 4);
    float*  rr      = (float*) alloc((size_t)HIDDEN * 4);
    float*  cvec    = (float*) alloc((size_t)64 * 4);
    ushort* GT      = (ushort*)alloc((size_t)64 * KDIM * 2);
    (void)ws_size; (void)n_in; (void)in_sizes; (void)out_size;

    hipMemsetAsync(deg, 0, (size_t)N_NODES * 4, stream);
    hipMemsetAsync(counter, 0, 4, stream);
    hipMemsetAsync(msum, 0, (size_t)KDIM * 4, stream);

    k_deg    <<<(N_EDGES + 255)/256, 256, 0, stream>>>(dst, deg, rank);
    k_rowptr <<<(N_NODES + 255)/256, 256, 0, stream>>>(deg, rowptr, nrm, counter);
    k_cast   <<<(N_NODES*16 + 255)/256, 256, 0, stream>>>(feats, nrm, Hx);
    k_scatter<<<8*SC_SLICES, 256, 0, stream>>>(src, dst, rowptr, rank, csr);

    int aggGrid = (N_NODES + 3) / 4;
    k_agg<true> <<<aggGrid, 256, 0, stream>>>(Hx,  H, 0,   HsB, rowptr, deg, nrm, csr);
    k_agg<true> <<<aggGrid, 256, 0, stream>>>(HsB, H, 64,  Hx,  rowptr, deg, nrm, csr);
    k_agg<false><<<aggGrid, 256, 0, stream>>>(Hx,  H, 128, HsB, rowptr, deg, nrm, csr);

    k_prepM<<<HIDDEN, KDIM, 0, stream>>>(W0, W1, W2, fcW, MT);
    k_bias <<<2, 256, 0, stream>>>(b0, b1, b2, fcW, fcb, Bc);

    k_hth   <<<NCHUNK, 256, 0, stream>>>(H, P, msum);
    dim3 rGrid(PPB/256, NSPLIT);
    k_reduce<<<rGrid, 256, 0, stream>>>(P, SP);
    k_finC  <<<NPAIR, 256, 0, stream>>>(SP, msum, C);
    k_cv    <<<HIDDEN, KDIM, 0, stream>>>(C, MT, V);
    k_solve2<<<1, HIDDEN, 0, stream>>>(V, MT, msum, Bc, gamma, beta, q, rr, cvec);
    k_buildG<<<64, KDIM, 0, stream>>>(MT, rr, q, GT);

    k_outgemm<<<NCHUNK, 256, 0, stream>>>(H, GT, cvec, out);
}

// Round 6
// 568.290 us; speedup vs baseline: 1.5989x; 1.0269x over previous
//
#include <hip/hip_runtime.h>
#include <hip/hip_bf16.h>
#include <stdint.h>

typedef unsigned short ushort;
typedef unsigned int uint;

#define N_NODES 100000
#define N_EDGES 1600000
#define KDIM 192      // 3 * 64 concatenated h_j
#define HIDDEN 512
#define NCHUNK 782    // ceil(N/128)
#define SDIM (KDIM*KDIM)
#define NPAIR 78      // 12*13/2 upper-triangle band pairs
#define PPB   9984    // uints per block partial: 78 frags * 128 uints
#define NSPLIT 8
#define LDT 194       // ushort stride of node-major LDS tile (192 + 2 pad)
#define NREG 8        // XCD-private histogram copies

typedef __attribute__((ext_vector_type(8))) short short8;
typedef __attribute__((ext_vector_type(4))) short short4v;
typedef __attribute__((ext_vector_type(4))) uint uint4v;
typedef __attribute__((ext_vector_type(4))) float float4v;
typedef __attribute__((ext_vector_type(2))) float float2v;
typedef __attribute__((ext_vector_type(2))) uint uint2v;

__device__ __forceinline__ float bf2f(ushort u){
    uint x = ((uint)u) << 16;
    return __builtin_bit_cast(float, x);
}
__device__ __forceinline__ float bflo(uint u){
    return __builtin_bit_cast(float, u << 16);
}
__device__ __forceinline__ float bfhi(uint u){
    return __builtin_bit_cast(float, u & 0xffff0000u);
}
__device__ __forceinline__ ushort f2bf(float f){
    uint u = __builtin_bit_cast(uint, f);
    u += 0x7fffu + ((u >> 16) & 1u);   // round-to-nearest-even
    return (ushort)(u >> 16);
}

// ---- 1. degree histogram into XCD-private copies + per-edge rank ----
// block b uses copy b&7; rank is exact because edge->copy is deterministic.
__global__ void k_deg(const int* __restrict__ dst, int* __restrict__ cnt,
                      int* __restrict__ rank){
    int b = blockIdx.x;
    int e = b * 256 + threadIdx.x;
    int* my = cnt + (size_t)(b & 7) * N_NODES;
    if (e < N_EDGES) rank[e] = atomicAdd(&my[dst[e]], 1);
}

// ---- 1b. total degree + in-place exclusive prefix across copies ----
__global__ void k_sumdeg(int* __restrict__ cnt, int* __restrict__ deg){
    int n = blockIdx.x * 256 + threadIdx.x;
    if (n >= N_NODES) return;
    int s = 0;
    #pragma unroll
    for (int r = 0; r < NREG; ++r){
        int c = cnt[(size_t)r*N_NODES + n];
        cnt[(size_t)r*N_NODES + n] = s;
        s += c;
    }
    deg[n] = s;
}

// ---- 2. per-node CSR base (block scan + 1 atomic/block), norm; fold base into copies ----
__global__ void k_rowptr(const int* __restrict__ deg, int* __restrict__ rowptr,
                         float* __restrict__ nrm, int* __restrict__ counter,
                         int* __restrict__ cnt){
    __shared__ int sc[256];
    __shared__ int sbase;
    int t = threadIdx.x;
    int n = blockIdx.x * 256 + t;
    int d = (n < N_NODES) ? deg[n] : 0;
    sc[t] = d; __syncthreads();
    for (int off = 1; off < 256; off <<= 1){
        int v = 0;
        if (t >= off) v = sc[t - off];
        __syncthreads();
        sc[t] += v;
        __syncthreads();
    }
    int incl = sc[t];
    int total = sc[255];
    int excl = incl - d;
    if (t == 0) sbase = atomicAdd(counter, total);
    __syncthreads();
    if (n < N_NODES){
        int base = sbase + excl;
        rowptr[n] = base;
        nrm[n] = rsqrtf((float)(d > 0 ? d : 1));
        #pragma unroll
        for (int r = 0; r < NREG; ++r)
            cnt[(size_t)r*N_NODES + n] += base;
    }
}

// ---- 3. cast feats to bf16 pre-scaled by nrm ----
__global__ void k_cast(const float* __restrict__ feats, const float* __restrict__ nrm,
                       ushort* __restrict__ Hx){
    int i = blockIdx.x * 256 + threadIdx.x;   // float4 groups, 16 per node
    if (i < N_NODES * 16){
        float w = nrm[i >> 4];
        float4v v = ((const float4v*)feats)[i];
        short4v o;
        o[0] = (short)f2bf(v[0]*w); o[1] = (short)f2bf(v[1]*w);
        o[2] = (short)f2bf(v[2]*w); o[3] = (short)f2bf(v[3]*w);
        ((short4v*)Hx)[i] = o;
    }
}

// ---- 4. scatter edges into CSR, XCD-affine by dst region ----
#define SC_SLICES 256
__global__ void k_scatter(const int* __restrict__ src, const int* __restrict__ dst,
                          const int* __restrict__ cnt, const int* __restrict__ rank,
                          int* __restrict__ csr){
    int b = blockIdx.x;
    int region = b & 7;
    int slice  = b >> 3;
    int lo = region * (N_NODES/8), hi = lo + (N_NODES/8);
    int e0 = slice * (N_EDGES/SC_SLICES);
    int e1 = e0 + (N_EDGES/SC_SLICES);
    for (int e = e0 + threadIdx.x; e < e1; e += 256){
        int d = dst[e];
        if (d >= lo && d < hi){
            int re = (e >> 8) & 7;
            csr[cnt[(size_t)re*N_NODES + d] + rank[e]] = src[e];
        }
    }
}

// ---- 5. aggregation: 8 lanes per edge row, dwordx4 gathers ----
template<bool WRITE_HS>
__global__ void k_agg(const ushort* __restrict__ inp,
                      ushort* __restrict__ H, int outoff,
                      ushort* __restrict__ Hs,
                      const int* __restrict__ rowptr, const int* __restrict__ deg,
                      const float* __restrict__ nrm, const int* __restrict__ csr){
    int node = (blockIdx.x << 2) + (threadIdx.x >> 6);
    int lane = threadIdx.x & 63;
    if (node >= N_NODES) return;
    int slot = lane >> 3;      // 0..7: edge slot
    int fb   = lane & 7;       // feature block (8 feats = 16B)
    int beg = rowptr[node];
    int d   = deg[node];
    float acc[8] = {};
    int i = 0;
    for (; i + 16 <= d; i += 16){
        int sA = csr[beg + i + slot];
        int sB = csr[beg + i + 8 + slot];
        uint4v vA = *(const uint4v*)(inp + (long)sA*64 + fb*8);
        uint4v vB = *(const uint4v*)(inp + (long)sB*64 + fb*8);
        #pragma unroll
        for (int p = 0; p < 4; ++p){
            acc[2*p]   += bflo(vA[p]); acc[2*p+1] += bfhi(vA[p]);
            acc[2*p]   += bflo(vB[p]); acc[2*p+1] += bfhi(vB[p]);
        }
    }
    if (i + 8 <= d){
        int sA = csr[beg + i + slot];
        uint4v vA = *(const uint4v*)(inp + (long)sA*64 + fb*8);
        #pragma unroll
        for (int p = 0; p < 4; ++p){
            acc[2*p]   += bflo(vA[p]); acc[2*p+1] += bfhi(vA[p]);
        }
        i += 8;
    }
    if (i < d){
        int e = i + slot;
        int s = csr[beg + (e < d ? e : d - 1)];
        uint4v v = *(const uint4v*)(inp + (long)s*64 + fb*8);
        if (e < d){
            #pragma unroll
            for (int p = 0; p < 4; ++p){
                acc[2*p]   += bflo(v[p]); acc[2*p+1] += bfhi(v[p]);
            }
        }
    }
    // reduce across the 8 slots
    #pragma unroll
    for (int k = 0; k < 8; ++k){
        acc[k] += __shfl_xor(acc[k], 8);
        acc[k] += __shfl_xor(acc[k], 16);
        acc[k] += __shfl_xor(acc[k], 32);
    }
    if (slot == 0){
        float wn = nrm[node];
        short8 o;
        #pragma unroll
        for (int k = 0; k < 8; ++k) o[k] = (short)f2bf(wn * acc[k]);
        *(short8*)(H + (long)node*KDIM + outoff + fb*8) = o;
        if (WRITE_HS){
            float w2 = wn * wn;
            short8 o2;
            #pragma unroll
            for (int k = 0; k < 8; ++k) o2[k] = (short)f2bf(w2 * acc[k]);
            *(short8*)(Hs + (long)node*64 + fb*8) = o2;
        }
    }
}

// ---- 6. fold weights: MT[c][64j+d] = sum_k Wj[k,d] * fcW[c, 512j+k] ----
__global__ void k_prepM(const float* __restrict__ W0, const float* __restrict__ W1,
                        const float* __restrict__ W2, const float* __restrict__ fcW,
                        ushort* __restrict__ MT){
    int c  = blockIdx.x;        // 0..511
    int jd = threadIdx.x;       // 0..191
    int j = jd >> 6, d = jd & 63;
    const float* W  = (j == 0) ? W0 : (j == 1) ? W1 : W2;
    const float* fw = fcW + (long)c*1536 + j*512;
    float s = 0.f;
    #pragma unroll 4
    for (int k = 0; k < 512; ++k) s += W[k*64 + d] * fw[k];
    MT[c*KDIM + jd] = f2bf(s);
}

// ---- 6b. folded bias ----
__global__ void k_bias(const float* __restrict__ b0, const float* __restrict__ b1,
                       const float* __restrict__ b2, const float* __restrict__ fcW,
                       const float* __restrict__ fcb, float* __restrict__ Bc){
    int c = blockIdx.x*256 + threadIdx.x;
    if (c >= HIDDEN) return;
    const float* fw = fcW + (long)c*1536;
    float s = fcb[c];
    for (int k = 0; k < 512; ++k)
        s += b0[k]*fw[k] + b1[k]*fw[512+k] + b2[k]*fw[1024+k];
    Bc[c] = s;
}

// ---- 7. symmetric H^T H: node-major LDS, 78 upper-tri band pairs ----
template<int W>
__device__ __forceinline__ void do_pairs(const short8* frag, float4v* acc){
    int p = 0, c = 0;
    #pragma unroll
    for (int i = 0; i < 12; ++i)
        #pragma unroll
        for (int j = i; j < 12; ++j){
            if ((p & 3) == W){
                acc[c] = __builtin_amdgcn_mfma_f32_16x16x32_bf16(frag[i], frag[j], acc[c], 0,0,0);
                ++c;
            }
            ++p;
        }
}
template<int W>
__device__ __forceinline__ void store_pairs(const float4v* acc, uint* Pb, int lane){
    int p = 0, c = 0;
    #pragma unroll
    for (int i = 0; i < 12; ++i)
        #pragma unroll
        for (int j = i; j < 12; ++j){
            if ((p & 3) == W){
                uint2v v;
                v[0] = (uint)f2bf(acc[c][0]) | ((uint)f2bf(acc[c][1]) << 16);
                v[1] = (uint)f2bf(acc[c][2]) | ((uint)f2bf(acc[c][3]) << 16);
                *(uint2v*)(Pb + p*128 + lane*2) = v;
                ++c;
            }
            ++p;
        }
}

__global__ __launch_bounds__(256, 2) void k_hth(const ushort* __restrict__ H,
                                                uint* __restrict__ P,
                                                float* __restrict__ msum){
    __shared__ ushort Ts[128*LDT];   // 49664 B, node-major
    int t = threadIdx.x;
    int w = t >> 6, lane = t & 63;
    int m16 = lane & 15, quad = lane >> 4;
    int n0 = blockIdx.x * 128;
    #pragma unroll
    for (int it = 0; it < 12; ++it){
        int flat = it*256 + t;           // 128 rows * 24 segs
        int row = flat / 24, seg = flat - row*24;
        int gr = n0 + row;
        short8 v = {0,0,0,0,0,0,0,0};
        if (gr < N_NODES) v = *(const short8*)(H + (long)gr*KDIM + seg*8);
        *(short8*)(Ts + row*LDT + seg*8) = v;
    }
    __syncthreads();
    float4v acc[20] = {};
    #pragma unroll
    for (int kt = 0; kt < 4; ++kt){
        short8 frag[12];
        #pragma unroll
        for (int b = 0; b < 12; ++b){
            short8 f;
            #pragma unroll
            for (int j = 0; j < 8; ++j)
                f[j] = (short)Ts[(kt*32 + quad*8 + j)*LDT + b*16 + m16];
            frag[b] = f;
        }
        if      (w == 0) do_pairs<0>(frag, acc);
        else if (w == 1) do_pairs<1>(frag, acc);
        else if (w == 2) do_pairs<2>(frag, acc);
        else             do_pairs<3>(frag, acc);
    }
    // folded column sums (Ts untouched since staging)
    if (t < KDIM){
        float s = 0.f;
        #pragma unroll 4
        for (int n = 0; n < 128; ++n) s += bf2f(Ts[n*LDT + t]);
        atomicAdd(&msum[t], s);
    }
    uint* Pb = P + (long)blockIdx.x * PPB;
    if      (w == 0) store_pairs<0>(acc, Pb, lane);
    else if (w == 1) store_pairs<1>(acc, Pb, lane);
    else if (w == 2) store_pairs<2>(acc, Pb, lane);
    else             store_pairs<3>(acc, Pb, lane);
}

// ---- 8. split-K reduce of partials (coalesced) ----
__global__ void k_reduce(const uint* __restrict__ P, float* __restrict__ SP){
    int p = blockIdx.x * 256 + threadIdx.x;   // 0..9983
    int y = blockIdx.y;
    int b0 = y * 98, b1 = min(b0 + 98, NCHUNK);
    float lo = 0.f, hi = 0.f;
    for (int b = b0; b < b1; ++b){
        uint v = P[(long)b*PPB + p];
        lo += bf2f((ushort)(v & 0xffff));
        hi += bf2f((ushort)(v >> 16));
    }
    float2v o; o[0] = lo; o[1] = hi;
    *(float2v*)(SP + (long)y*(NPAIR*256) + p*2) = o;
}

// ---- 9. finalize covariance C (both triangles) from fragment layout ----
__global__ void k_finC(const float* __restrict__ SP, const float* __restrict__ msum,
                       float* __restrict__ C){
    int idx = blockIdx.x * 256 + threadIdx.x;   // 0..19967
    float s = 0.f;
    #pragma unroll
    for (int y = 0; y < NSPLIT; ++y) s += SP[(long)y*(NPAIR*256) + idx];
    int h = idx & 1, pu = idx >> 1;
    int p = pu >> 7, rem = pu & 127;
    int l = rem >> 1, u = rem & 1;
    int r = u*2 + h;
    int pi = 0, pj = 0, off = 0;
    #pragma unroll
    for (int k = 0; k < 12; ++k){
        int len = 12 - k;
        if (p >= off && p < off + len){ pi = k; pj = k + (p - off); }
        off += len;
    }
    int m = pi*16 + (l >> 4)*4 + r;
    int n = pj*16 + (l & 15);
    const float invN = 1.f / (float)N_NODES;
    float v = s*invN - (msum[m]*invN)*(msum[n]*invN);
    C[m*KDIM + n] = v;
    C[n*KDIM + m] = v;
}

// ---- 10. V[c] = C @ M_c ----
__global__ void k_cv(const float* __restrict__ C, const ushort* __restrict__ MT,
                     float* __restrict__ V){
    int c = blockIdx.x, d = threadIdx.x;  // 512 x 192
    const ushort* mt = MT + c*KDIM;
    float s = 0.f;
    #pragma unroll 4
    for (int dp = 0; dp < KDIM; ++dp)
        s += bf2f(mt[dp]) * C[dp*KDIM + d];
    V[c*KDIM + d] = s;
}

// ---- 11. BN solve: r_c, cvec ----
__global__ void k_solve2(const float* __restrict__ V, const ushort* __restrict__ MT,
                         const float* __restrict__ msum, const float* __restrict__ Bc,
                         const float* __restrict__ gamma, const float* __restrict__ beta,
                         const float* __restrict__ q,
                         float* __restrict__ rr, float* __restrict__ cvec){
    __shared__ float tmp[HIDDEN];
    int c = threadIdx.x;  // 0..511
    const float invN = 1.f / (float)N_NODES;
    float mu = Bc[c], var = 0.f;
    const ushort* mt = MT + c*KDIM;
    const float* vc = V + c*KDIM;
    #pragma unroll 4
    for (int d = 0; d < KDIM; ++d){
        float m = bf2f(mt[d]);
        mu  += msum[d]*invN * m;
        var += vc[d] * m;
    }
    float r = gamma[c] * rsqrtf(var + 1e-5f);
    rr[c] = r;
    tmp[c] = r * (Bc[c] - mu) + beta[c];
    __syncthreads();
    if (c < 64){
        float s = 0.f;
        #pragma unroll
        for (int k = 0; k < 8; ++k) s += q[k] * tmp[k*64 + c];
        cvec[c] = s;
    }
}

// ---- 12. fold rho into M: GT[o][d] = sum_k q_k r_{k64+o} MT[k64+o][d] ----
__global__ void k_buildG(const ushort* __restrict__ MT, const float* __restrict__ rr,
                         const float* __restrict__ q, ushort* __restrict__ GT){
    int o = blockIdx.x, d = threadIdx.x;  // 64 x 192
    float s = 0.f;
    #pragma unroll
    for (int k = 0; k < 8; ++k)
        s += q[k] * rr[k*64 + o] * bf2f(MT[(k*64 + o)*KDIM + d]);
    GT[o*KDIM + d] = f2bf(s);
}

// ---- 13. out = H @ GT^T + cvec ----
#define LDA 200
__global__ __launch_bounds__(256) void k_outgemm(const ushort* __restrict__ H,
                                                 const ushort* __restrict__ GT,
                                                 const float* __restrict__ cvec,
                                                 float* __restrict__ out){
    __shared__ ushort As[128*LDA];
    __shared__ ushort Gs[64*LDA];
    int t = threadIdx.x;
    int n0 = blockIdx.x * 128;
    int w = t >> 6, lane = t & 63;
    int m16 = lane & 15, quad = lane >> 4;
    int wr = w * 32;
    float4v acc[2][4] = {};
    #pragma unroll
    for (int it = 0; it < 12; ++it){
        int flat = it*256 + t;               // 128 rows * 24 segs
        int row = flat / 24, seg = flat - row*24;
        int gr = n0 + row;
        short8 v = {0,0,0,0,0,0,0,0};
        if (gr < N_NODES) v = *(const short8*)(H + (long)gr*KDIM + seg*8);
        *(short8*)(As + row*LDA + seg*8) = v;
    }
    #pragma unroll
    for (int it = 0; it < 6; ++it){
        int flat = it*256 + t;               // 64 rows * 24 segs
        int row = flat / 24, seg = flat - row*24;
        short8 v = *(const short8*)(GT + row*KDIM + seg*8);
        *(short8*)(Gs + row*LDA + seg*8) = v;
    }
    __syncthreads();
    #pragma unroll
    for (int kk = 0; kk < 192; kk += 32){
        short8 af[2], bf[4];
        #pragma unroll
        for (int i = 0; i < 2; ++i)
            af[i] = *(const short8*)(As + (wr + i*16 + m16)*LDA + kk + quad*8);
        #pragma unroll
        for (int j = 0; j < 4; ++j)
            bf[j] = *(const short8*)(Gs + (j*16 + m16)*LDA + kk + quad*8);
        #pragma unroll
        for (int i = 0; i < 2; ++i)
            #pragma unroll
            for (int j = 0; j < 4; ++j)
                acc[i][j] = __builtin_amdgcn_mfma_f32_16x16x32_bf16(af[i], bf[j], acc[i][j], 0,0,0);
    }
    #pragma unroll
    for (int i = 0; i < 2; ++i)
        #pragma unroll
        for (int j = 0; j < 4; ++j)
            #pragma unroll
            for (int r = 0; r < 4; ++r){
                int rowg = n0 + wr + i*16 + quad*4 + r;
                int o = j*16 + m16;
                if (rowg < N_NODES) out[(long)rowg*64 + o] = acc[i][j][r] + cvec[o];
            }
}

extern "C" void kernel_launch(void* const* d_in, const int* in_sizes, int n_in,
                              void* d_out, int out_size, void* d_ws, size_t ws_size,
                              hipStream_t stream) {
    const float* feats = (const float*)d_in[0];
    const int*   src   = (const int*)  d_in[1];
    const int*   dst   = (const int*)  d_in[2];
    const float* W0    = (const float*)d_in[3];
    const float* b0    = (const float*)d_in[4];
    const float* W1    = (const float*)d_in[5];
    const float* b1    = (const float*)d_in[6];
    const float* W2    = (const float*)d_in[7];
    const float* b2    = (const float*)d_in[8];
    const float* fcW   = (const float*)d_in[9];
    const float* fcb   = (const float*)d_in[10];
    const float* gamma = (const float*)d_in[11];
    const float* beta  = (const float*)d_in[12];
    const float* q     = (const float*)d_in[13];
    float* out = (float*)d_out;

    char* ws = (char*)d_ws;
    size_t off = 0;
    auto alloc = [&](size_t bytes) -> char* {
        char* p = ws + off;
        off = (off + bytes + 511) & ~(size_t)511;
        return p;
    };
    int*    cnt     = (int*)   alloc((size_t)NREG * N_NODES * 4);
    int*    deg     = (int*)   alloc((size_t)N_NODES * 4);
    int*    rowptr  = (int*)   alloc((size_t)N_NODES * 4);
    float*  nrm     = (float*) alloc((size_t)N_NODES * 4);
    int*    counter = (int*)   alloc(256);
    int*    rank    = (int*)   alloc((size_t)N_EDGES * 4);
    int*    csr     = (int*)   alloc((size_t)N_EDGES * 4);
    ushort* Hx      = (ushort*)alloc((size_t)N_NODES * 64 * 2);
    ushort* HsB     = (ushort*)alloc((size_t)N_NODES * 64 * 2);
    ushort* H       = (ushort*)alloc((size_t)N_NODES * KDIM * 2);
    ushort* MT      = (ushort*)alloc((size_t)HIDDEN * KDIM * 2);
    float*  Bc      = (float*) alloc((size_t)HIDDEN * 4);
    float*  msum    = (float*) alloc((size_t)KDIM * 4);
    uint*   P       = (uint*)  alloc((size_t)NCHUNK * PPB * 4);
    float*  SP      = (float*) alloc((size_t)NSPLIT * NPAIR * 256 * 4);
    float*  C       = (float*) alloc((size_t)SDIM * 4);
    float*  V       = (float*) alloc((size_t)HIDDEN * KDIM * 4);
    float*  rr      = (float*) alloc((size_t)HIDDEN * 4);
    float*  cvec    = (float*) alloc((size_t)64 * 4);
    ushort* GT      = (ushort*)alloc((size_t)64 * KDIM * 2);
    (void)ws_size; (void)n_in; (void)in_sizes; (void)out_size;

    hipMemsetAsync(cnt, 0, (size_t)NREG * N_NODES * 4, stream);
    hipMemsetAsync(counter, 0, 4, stream);
    hipMemsetAsync(msum, 0, (size_t)KDIM * 4, stream);

    k_deg    <<<(N_EDGES + 255)/256, 256, 0, stream>>>(dst, cnt, rank);
    k_sumdeg <<<(N_NODES + 255)/256, 256, 0, stream>>>(cnt, deg);
    k_rowptr <<<(N_NODES + 255)/256, 256, 0, stream>>>(deg, rowptr, nrm, counter, cnt);
    k_cast   <<<(N_NODES*16 + 255)/256, 256, 0, stream>>>(feats, nrm, Hx);
    k_scatter<<<8*SC_SLICES, 256, 0, stream>>>(src, dst, cnt, rank, csr);

    int aggGrid = (N_NODES + 3) / 4;
    k_agg<true> <<<aggGrid, 256, 0, stream>>>(Hx,  H, 0,   HsB, rowptr, deg, nrm, csr);
    k_agg<true> <<<aggGrid, 256, 0, stream>>>(HsB, H, 64,  Hx,  rowptr, deg, nrm, csr);
    k_agg<false><<<aggGrid, 256, 0, stream>>>(Hx,  H, 128, HsB, rowptr, deg, nrm, csr);

    k_prepM<<<HIDDEN, KDIM, 0, stream>>>(W0, W1, W2, fcW, MT);
    k_bias <<<2, 256, 0, stream>>>(b0, b1, b2, fcW, fcb, Bc);

    k_hth   <<<NCHUNK, 256, 0, stream>>>(H, P, msum);
    dim3 rGrid(PPB/256, NSPLIT);
    k_reduce<<<rGrid, 256, 0, stream>>>(P, SP);
    k_finC  <<<NPAIR, 256, 0, stream>>>(SP, msum, C);
    k_cv    <<<HIDDEN, KDIM, 0, stream>>>(C, MT, V);
    k_solve2<<<1, HIDDEN, 0, stream>>>(V, MT, msum, Bc, gamma, beta, q, rr, cvec);
    k_buildG<<<64, KDIM, 0, stream>>>(MT, rr, q, GT);

    k_outgemm<<<NCHUNK, 256, 0, stream>>>(H, GT, cvec, out);
}